// Round 6
// baseline (13816.905 us; speedup 1.0000x reference)
//
#include <hip/hip_runtime.h>

// Problem dims
#define Lz   128
#define Hd   1024
#define Od   64
#define Sq   256
#define Bt   512
#define K1   1216   // W1 cols: h1(1024) | z(128) | out(64)
#define K2q  2048   // W2 cols: h1n(1024) | h2(1024)
#define G4H  4096
#define NBLK 256u   // 4 pairs x 64 blocks (2 XCDs x 32); dynamic team formation
#define A1LS (128*1024)   // shorts per XCD-local A1 copy (h1 slot only)
#define A2LS (128*2048)   // shorts per XCD-local A2 copy

typedef __attribute__((ext_vector_type(8))) short  short8;
typedef __attribute__((ext_vector_type(4))) float  floatx4;

__device__ __forceinline__ short f2bf(float x) {
  unsigned u = __float_as_uint(x);
  unsigned r = (u + 0x7fffu + ((u >> 16) & 1u)) >> 16;
  return (short)r;
}
__device__ __forceinline__ float sigf(float x)   { return 1.0f / (1.0f + __expf(-x)); }
__device__ __forceinline__ float tanhf_(float x) { return 1.0f - 2.0f / (__expf(2.0f * x) + 1.0f); }

// cached load (weights, z): allocate in L2 -> dedups the 2x mh-redundancy
__device__ __forceinline__ void gl_lds_c(const short* g, void* l) {
  __builtin_amdgcn_global_load_lds(
      (__attribute__((address_space(1))) const void*)g,
      (__attribute__((address_space(3))) void*)l, 16, 0, 0);
}
// XCD-local activation load: sc0 -> bypass L1, hit own XCD's L2 dirty lines
__device__ __forceinline__ void gl_lds_a(const short* g, void* l) {
  __builtin_amdgcn_global_load_lds(
      (__attribute__((address_space(1))) const void*)g,
      (__attribute__((address_space(3))) void*)l, 16, 0, 1);
}
// cross-XCD forced-miss load (out-feedback chunk): sc0|sc1|nt -> reads MALL
__device__ __forceinline__ void gl_lds_f(const short* g, void* l) {
  __builtin_amdgcn_global_load_lds(
      (__attribute__((address_space(1))) const void*)g,
      (__attribute__((address_space(3))) void*)l, 16, 0, 19);
}
// local store (own-XCD L2, intra-XCD coherent for sc0 readers)
__device__ __forceinline__ void st_l(short* p, short v) {
  asm volatile("global_store_short %0, %1, off sc0"
               :: "v"(p), "v"((unsigned)(unsigned short)v) : "memory");
}
// write-through store (visible at MALL to the partner XCD)
__device__ __forceinline__ void st_g(short* p, short v) {
  asm volatile("global_store_short %0, %1, off sc0 sc1"
               :: "v"(p), "v"((unsigned)(unsigned short)v) : "memory");
}

#define S_BARRIER() asm volatile("s_barrier" ::: "memory")
#define WAITVM(n)   asm volatile("s_waitcnt vmcnt(" #n ")" ::: "memory")

// ---- per-pair barrier over 64 blocks (relaxed agent atomics, proven pattern)
__device__ __forceinline__ void xbar(int* b) {   // b: [cnt, gen]
  __syncthreads();
  if (threadIdx.x == 0) {
    unsigned* cnt = (unsigned*)b;
    unsigned* gen = (unsigned*)b + 1;
    unsigned g = __hip_atomic_load(gen, __ATOMIC_RELAXED, __HIP_MEMORY_SCOPE_AGENT);
    unsigned a = __hip_atomic_fetch_add(cnt, 1u, __ATOMIC_RELAXED, __HIP_MEMORY_SCOPE_AGENT);
    if (a == 63u) {
      __hip_atomic_store(cnt, 0u, __ATOMIC_RELAXED, __HIP_MEMORY_SCOPE_AGENT);
      __hip_atomic_store(gen, g + 1u, __ATOMIC_RELAXED, __HIP_MEMORY_SCOPE_AGENT);
    } else {
      while (__hip_atomic_load(gen, __ATOMIC_RELAXED, __HIP_MEMORY_SCOPE_AGENT) == g)
        __builtin_amdgcn_s_sleep(8);
    }
  }
  __syncthreads();
}

// ---- weight row reorder: group bn (0..63) holds 64 rows: gate g (ifgo), j (0..15)
__device__ __forceinline__ int oldrow(int nr) {
  int bn = nr >> 6, rem = nr & 63, g = rem >> 4, jj = rem & 15;
  return g * Hd + bn * 16 + jj;
}

struct Params {
  const short *W1r, *W2r, *Woutb;
  const float *b0v, *b1v, *bout;
  short *A1L, *A2L;          // [2 parity][8 xcd] XCD-local activation copies
  short *E1, *E2, *Eout, *Zb; // shared exchange buffers + static z (bf16)
  float *c1, *c2, *out;
  int *barr;   // per-pair [pid*16]: cnt,gen,outcnt; slot counters at [128+xcc]
};

// ================= prep kernels =================
__global__ void k_conv_w1a(const float* __restrict__ Whh0, short* __restrict__ W1r) {
  int idx = blockIdx.x * 256 + threadIdx.x;        // 4096*1024
  int nr = idx >> 10, k = idx & 1023;
  W1r[nr * K1 + k] = f2bf(Whh0[oldrow(nr) * Hd + k]);
}
__global__ void k_conv_w1c(const float* __restrict__ Wih0, short* __restrict__ W1r) {
  int idx = blockIdx.x * 256 + threadIdx.x;        // 4096*128 (z cols)
  int nr = idx >> 7, kz = idx & 127;
  W1r[nr * K1 + 1024 + kz] = f2bf(Wih0[oldrow(nr) * (Lz + Od) + kz]);
}
__global__ void k_conv_w1d(const float* __restrict__ Wih0, short* __restrict__ W1r) {
  int idx = blockIdx.x * 256 + threadIdx.x;        // 4096*64 (out-feedback cols)
  int nr = idx >> 6, j = idx & 63;
  W1r[nr * K1 + 1152 + j] = f2bf(Wih0[oldrow(nr) * (Lz + Od) + Lz + j]);
}
__global__ void k_conv_w2(const float* __restrict__ Wih1, const float* __restrict__ Whh1,
                          short* __restrict__ W2r) {
  int idx = blockIdx.x * 256 + threadIdx.x;        // 4096*2048
  int nr = idx >> 11, k = idx & 2047;
  int orow = oldrow(nr);
  float v = (k < Hd) ? Wih1[orow * Hd + k] : Whh1[orow * Hd + (k - Hd)];
  W2r[nr * K2q + k] = f2bf(v);
}
__global__ void k_conv_wout(const float* __restrict__ Wout, short* __restrict__ Woutb) {
  int idx = blockIdx.x * 256 + threadIdx.x;        // 64*1024
  Woutb[idx] = f2bf(Wout[idx]);
}
__global__ void k_vec(const float* __restrict__ bih0, const float* __restrict__ bhh0,
                      const float* __restrict__ bih1, const float* __restrict__ bhh1,
                      float* __restrict__ b0v, float* __restrict__ b1v,
                      int* __restrict__ barzero, int* __restrict__ eoutz) {
  int n = blockIdx.x * 256 + threadIdx.x;          // 4096 (original gate order)
  if (n < 256) barzero[n] = 0;                     // barrier/team/outcnt state
  #pragma unroll
  for (int j = 0; j < 4; ++j) eoutz[n * 4 + j] = 0;  // zero Eout (out(-1) = 0)
  b0v[n] = bih0[n] + bhh0[n];
  b1v[n] = bih1[n] + bhh1[n];
}
__global__ void k_init(const float* __restrict__ z, const float* __restrict__ Wh,
                       const float* __restrict__ bh, const float* __restrict__ Wc,
                       const float* __restrict__ bc,
                       short* __restrict__ A1L, short* __restrict__ A2L,
                       float* __restrict__ c1, float* __restrict__ c2) {
  int idx = blockIdx.x * 256 + threadIdx.x;        // 512*1024
  int m = idx >> 10, n = idx & 1023;
  const float* zr = z + m * Lz;
  const float* whr = Wh + n * Lz;
  const float* wcr = Wc + n * Lz;
  float hh = bh[n], cc = bc[n];
  #pragma unroll 8
  for (int k = 0; k < Lz; ++k) { float zv = zr[k]; hh += zv * whr[k]; cc += zv * wcr[k]; }
  c1[idx] = cc;
  c2[idx] = cc;
  short hb = f2bf(hh);
  int x0 = (m >> 7) * 2, lr = m & 127;             // pair pid=m>>7 -> XCDs x0,x0+1
  short* a1 = A1L + ((size_t)0 * 8 + x0) * A1LS + (size_t)lr * 1024 + n;
  a1[0] = hb; a1[A1LS] = hb;                       // h1(-1)=h0, both pair XCDs (parity 0)
  short* a2 = A2L + ((size_t)x0) * A2LS + (size_t)lr * 2048 + 1024 + n;
  a2[0] = hb; a2[A2LS] = hb;                       // h2(-1)=h0, both pair XCDs (parity 0)
}
__global__ void k_zb(const float* __restrict__ z, short* __restrict__ Zb) {
  int idx = blockIdx.x * 256 + threadIdx.x;        // 512*128
  Zb[idx] = f2bf(z[idx]);
}

// ================= main persistent kernel =================
#define MFMA16(a, b, c) __builtin_amdgcn_mfma_f32_16x16x32_bf16(a, b, c, 0, 0, 0)
#define BUFSH 12288   // shorts per ring buffer: A 64x64 (4096) + W 128x64 (8192)
#define NBUF  4       // prefetch depth 3
#define LDS_BYTES (NBUF * BUFSH * 2)   // 96 KB -> exactly 1 block/CU

// ---- exchange copy: partner's 512-col half of one E row-block -> local copies.
// Block `slot` copies pair-local rows slot*4..+3 (4KB): forced-miss read from
// MALL (write-through-published), sc0 store into own-XCD private buffer(s).
__device__ __forceinline__ void xchg(const short* __restrict__ Esrc,  // pair-base
    short* __restrict__ d0, int s0, int o0,
    short* __restrict__ d1, int xhalf, int slot, int tid)
{
  const int row = slot * 4 + (tid >> 6);
  const int col = ((xhalf ^ 1) << 9) + (tid & 63) * 8;
  const short* src = Esrc + (size_t)row * 1024 + col;
  short8 v;
  asm volatile("global_load_dwordx4 %0, %1, off sc0 sc1 nt"
               : "=v"(v) : "v"(src) : "memory");
  WAITVM(0);
  short* p0 = d0 + (size_t)row * s0 + o0 + col;
  asm volatile("global_store_dwordx4 %0, %1, off sc0" :: "v"(p0), "v"(v) : "memory");
  if (d1) {
    short* p1 = d1 + (size_t)row * 1024 + col;
    asm volatile("global_store_dwordx4 %0, %1, off sc0" :: "v"(p1), "v"(v) : "memory");
  }
  WAITVM(0);
}

// ---- folded out-projection, register-based (R2-proven pipeline): 4 jobs/XCD,
// 16 pair-local rows each; h2 from own-XCD L2 (sc0); Wout cached.
__device__ __forceinline__ void out_reg(const short* __restrict__ A2c,
    const short* __restrict__ Wo, const float* __restrict__ boutv,
    float* __restrict__ outp, int tt, int mo, int pid,
    short* __restrict__ eout, int tid, int* __restrict__ ocnt)
{
  const int lane = tid & 63, w = tid >> 6;
  const int l15 = lane & 15, q = lane >> 4;
  const short* ap = A2c + (size_t)(mo + l15) * 2048 + 1024 + q * 8;
  const short* bp = Wo + (size_t)(w * 16 + l15) * Hd + q * 8;
  floatx4 acc = {};
  short8 A0, B0, A1, B1, A2, B2, A3, B3;
#define OLA(r, kk) asm volatile("global_load_dwordx4 %0, %1, off sc0" \
    : "=v"(r) : "v"(ap + (kk) * 32) : "memory")
#define OLB(r, kk) asm volatile("global_load_dwordx4 %0, %1, off" \
    : "=v"(r) : "v"(bp + (kk) * 32) : "memory")
  OLA(A0, 0); OLB(B0, 0); OLA(A1, 1); OLB(B1, 1);     // group 0 (kk 0,1)
  OLA(A2, 2); OLB(B2, 2); OLA(A3, 3); OLB(B3, 3);     // group 1 (kk 2,3)
  #pragma unroll
  for (int g = 0; g < 16; g += 2) {
    WAITVM(4); __builtin_amdgcn_sched_barrier(0);      // group g retired
    acc = MFMA16(A0, B0, acc); acc = MFMA16(A1, B1, acc);
    if (g + 2 < 16) { OLA(A0, 2*(g+2)); OLB(B0, 2*(g+2));
                      OLA(A1, 2*(g+2)+1); OLB(B1, 2*(g+2)+1); }
    if (g + 3 < 16) { WAITVM(4); } else { WAITVM(0); } // group g+1 retired
    __builtin_amdgcn_sched_barrier(0);
    acc = MFMA16(A2, B2, acc); acc = MFMA16(A3, B3, acc);
    if (g + 3 < 16) { OLA(A2, 2*(g+3)); OLB(B2, 2*(g+3));
                      OLA(A3, 2*(g+3)+1); OLB(B3, 2*(g+3)+1); }
  }
#undef OLA
#undef OLB
  #pragma unroll
  for (int r = 0; r < 4; ++r) {
    int m = mo + q * 4 + r;                 // pair-local
    int n = w * 16 + l15;
    float v = acc[r] + boutv[n];
    outp[(size_t)(pid * 128 + m) * (Sq * Od) + (size_t)tt * Od + n] = v;
    if (eout) st_g(eout + (size_t)m * 64 + n, f2bf(v));
  }
  WAITVM(0);          // drain write-through feedback
  __syncthreads();
  if (ocnt && tid == 0)
    __hip_atomic_fetch_add(ocnt, 1, __ATOMIC_RELAXED, __HIP_MEMORY_SCOPE_AGENT);
}

// 64x128 tile, 4 waves (R0-proven core), ring NBUF=4 depth 3.
// MODE 1 = layer-0 window: A = [h1(local) | z(cached) | out(forced-miss,guarded)]
// MODE 0 = layer-1 window: A = A2 local (stride 2048)
template<int MODE>
__device__ __forceinline__ void gemm_win(
    const short* __restrict__ pA,      // A source, pre-offset by mrow0*stride
    const short* __restrict__ pZ,      // MODE1: z rows (pre-offset, stride 128)
    const short* __restrict__ pEo,     // MODE1: out rows (pre-offset, stride 64)
    const short* __restrict__ Wsrc,
    const float* __restrict__ bz, float cr[2][4],
    short* __restrict__ hd0, int hs0, int ho0,   // local target 0 (st_l)
    short* __restrict__ hd1, int hs1,            // MODE1 local target 1 or null
    short* __restrict__ hg,                      // write-through target (pair-base)
    int mrow0, int bn2, short* sm, int tid,
    int* __restrict__ ocnt, int othresh)
{
  const int nk = MODE ? 19 : 32;
  const int wstr = MODE ? K1 : K2q;
  const int astr = MODE ? 1024 : 2048;
  const int lane = tid & 63, w = tid >> 6;
  const int l15 = lane & 15, q = lane >> 4;
  const int mh = w >> 1, gh = w & 1;
  floatx4 acc[2][4] = {};

  const short* Wb = Wsrc + (size_t)(bn2 * 128) * wstr;

  auto stage = [&](int kk, int b) {
    short* as = sm + b * BUFSH;
    short* ws = as + 4096;
    #pragma unroll
    for (int i = 0; i < 2; ++i) {
      int s = i * 256 + tid;
      int row = s >> 3, cg = (s & 7) ^ (row & 7);
      if (MODE == 1) {
        if (kk < 16)      gl_lds_a(pA + (size_t)row * astr + kk * 64 + cg * 8, as + s * 8);
        else if (kk < 18) gl_lds_c(pZ + (size_t)row * 128 + (kk - 16) * 64 + cg * 8, as + s * 8);
        else              gl_lds_f(pEo + (size_t)row * 64 + cg * 8, as + s * 8);
      } else {
        gl_lds_a(pA + (size_t)row * astr + kk * 64 + cg * 8, as + s * 8);
      }
    }
    #pragma unroll
    for (int i = 0; i < 4; ++i) {
      int s = i * 256 + tid;
      int row = s >> 3, cg = (s & 7) ^ (row & 7);
      gl_lds_c(Wb + (size_t)row * wstr + kk * 64 + cg * 8, ws + s * 8);
    }
  };

  stage(0, 0);
  stage(1, 1);
  stage(2, 2);
  for (int kk = 0; kk < nk; ++kk) {
    S_BARRIER();
    if (kk + 3 < nk) {
      if (MODE == 1 && ocnt && kk + 3 == nk - 1) {   // out chunk: wait for out-jobs
        while (__hip_atomic_load(ocnt, __ATOMIC_RELAXED, __HIP_MEMORY_SCOPE_AGENT) < othresh)
          __builtin_amdgcn_s_sleep(1);
      }
      stage(kk + 3, (kk + 3) & 3);
      WAITVM(18);
    }
    else if (kk + 2 < nk) { WAITVM(12); }
    else if (kk + 1 < nk) { WAITVM(6); }
    else { WAITVM(0); }
    S_BARRIER();
    const short* as = sm + (kk & 3) * BUFSH;
    const short* ws = as + 4096;
    #pragma unroll
    for (int ks = 0; ks < 2; ++ks) {
      const int cc = ks * 4 + q;
      short8 a[2];
      #pragma unroll
      for (int mt = 0; mt < 2; ++mt) {
        const int ra = mh * 32 + mt * 16 + l15;
        a[mt] = *(const short8*)(as + (ra * 8 + (cc ^ (ra & 7))) * 8);
      }
      #pragma unroll
      for (int g = 0; g < 4; ++g) {
        const int rw = gh * 64 + g * 16 + l15;
        short8 b = *(const short8*)(ws + (rw * 8 + (cc ^ (rw & 7))) * 8);
        acc[0][g] = MFMA16(a[0], b, acc[0][g]);
        acc[1][g] = MFMA16(a[1], b, acc[1][g]);
      }
    }
  }
  // fused LSTM cell epilogue: local store(s) + write-through exchange copy
  const int colh = bn2 * 32 + gh * 16 + l15;
  #pragma unroll
  for (int mt = 0; mt < 2; ++mt) {
    #pragma unroll
    for (int r = 0; r < 4; ++r) {
      const int mg = mrow0 + mh * 32 + mt * 16 + q * 4 + r;   // pair-local row
      float iv = acc[mt][0][r] + bz[0];
      float fv = acc[mt][1][r] + bz[1];
      float gv = acc[mt][2][r] + bz[2];
      float ov = acc[mt][3][r] + bz[3];
      float cn = sigf(fv) * cr[mt][r] + sigf(iv) * tanhf_(gv);
      cr[mt][r] = cn;
      short hb = f2bf(sigf(ov) * tanhf_(cn));
      st_l(hd0 + (size_t)mg * hs0 + ho0 + colh, hb);
      if (MODE == 1) st_l(hd1 + (size_t)mg * hs1 + colh, hb);
      st_g(hg + (size_t)mg * 1024 + colh, hb);
    }
  }
}

__global__ __launch_bounds__(256, 1) void lstm_main(Params p) {
  extern __shared__ __align__(16) short smem[];   // 4 x 24 KB = 96 KB
  const int tid = threadIdx.x;

  // ---- dynamic team formation: block joins the XCD it runs on (1 block/CU
  // guaranteed by 96KB LDS -> exactly 32 blocks/XCD, 64 per pair).
  __shared__ int sh_ids[2];
  if (tid == 0) {
    unsigned xr;
    asm volatile("s_getreg_b32 %0, hwreg(HW_REG_XCC_ID)" : "=s"(xr));
    int xcc = (int)(xr & 7u);
    int slot = (int)__hip_atomic_fetch_add((unsigned*)(p.barr + 128 + xcc), 1u,
                                           __ATOMIC_RELAXED, __HIP_MEMORY_SCOPE_AGENT);
    sh_ids[0] = xcc;
    sh_ids[1] = slot & 31;
  }
  __syncthreads();
  const int xcc   = sh_ids[0];
  const int slot  = sh_ids[1];
  const int pid   = xcc >> 1;           // pair id 0..3; batch rows [pid*128,+128)
  const int xhalf = xcc & 1;            // gate-half within pair
  int* pb = p.barr + pid * 16;          // [0]=cnt [1]=gen [2]=outcnt (per pair)

  const int bn2 = xhalf * 16 + (slot & 15);   // 0..31 pair-scoped gate-col slice
  const int mrow0 = (slot >> 4) * 64;         // pair-local m-tile base (0 or 64)
  const bool ojob = ((slot & 7) == 0);        // 4 out-jobs per XCD, 8 per pair
  const int mo = (xhalf * 4 + (slot >> 3)) * 16;  // out-job pair-local rows
  const int grow = pid * 128;                 // pair's global row base

  const int lane = tid & 63, w = tid >> 6;
  const int l15 = lane & 15, q = lane >> 4;
  const int mh = w >> 1, gh = w & 1;
  const int colh = bn2 * 32 + gh * 16 + l15;

  short* E1p = p.E1 + (size_t)grow * 1024;
  short* E2p = p.E2 + (size_t)grow * 1024;
  short* Eoutp = p.Eout + (size_t)grow * 64;
  const short* Zp  = p.Zb + (size_t)(grow + mrow0) * 128;
  const short* Eop = p.Eout + (size_t)(grow + mrow0) * 64;

  float bA[4], bB[4], c1r[2][4], c2r[2][4];
  #pragma unroll
  for (int g = 0; g < 4; ++g) {
    bA[g] = p.b0v[g * Hd + colh];
    bB[g] = p.b1v[g * Hd + colh];
  }
  #pragma unroll
  for (int mt = 0; mt < 2; ++mt)
    #pragma unroll
    for (int r = 0; r < 4; ++r) {
      const int mg = grow + mrow0 + mh * 32 + mt * 16 + q * 4 + r;
      c1r[mt][r] = p.c1[mg * Hd + colh];
      c2r[mt][r] = p.c2[mg * Hd + colh];
    }

  for (int t = 0; t < Sq; ++t) {
    const int par = t & 1;
    short* A1c = p.A1L + ((size_t)par * 8 + xcc) * A1LS;
    short* A1n = p.A1L + ((size_t)(par ^ 1) * 8 + xcc) * A1LS;
    short* A2c = p.A2L + ((size_t)par * 8 + xcc) * A2LS;
    short* A2n = p.A2L + ((size_t)(par ^ 1) * 8 + xcc) * A2LS;

    if (t > 0) {
      // exchange h2(t-1): partner half E2 -> own A2c h2 slot; then out-jobs.
      xchg(E2p, A2c, 2048, 1024, (short*)nullptr, xhalf, slot, tid);
      xbar(pb);
      if (ojob)
        out_reg(A2c, p.Woutb, p.bout, p.out, t - 1, mo, pid, Eoutp, tid, pb + 2);
    }
    // window A: layer-0 gates. h1n -> A1n(local) + A2c h1n slot(local) + E1(WT)
    gemm_win<1>(A1c + (size_t)mrow0 * 1024, Zp, Eop, p.W1r, bA, c1r,
                A1n, 1024, 0, A2c, 2048, E1p,
                mrow0, bn2, smem, tid, pb + 2, 8 * t);
    xbar(pb);
    // exchange h1n: partner half E1 -> own A2c h1n slot + A1n h1 slot
    xchg(E1p, A2c, 2048, 0, A1n, xhalf, slot, tid);
    xbar(pb);
    // window B: layer-1 gates. h2 -> A2n h2 slot(local) + E2(WT)
    gemm_win<0>(A2c + (size_t)mrow0 * 2048, (const short*)nullptr, (const short*)nullptr,
                p.W2r, bB, c2r,
                A2n, 2048, 1024, (short*)nullptr, 0, E2p,
                mrow0, bn2, smem, tid, nullptr, 0);
    xbar(pb);
  }
  // final: out(255) from h2(255) (winB(255) wrote parity-0 locals + E2)
  {
    short* A2f = p.A2L + (size_t)xcc * A2LS;    // parity 0
    xchg(E2p, A2f, 2048, 1024, (short*)nullptr, xhalf, slot, tid);
    xbar(pb);
    if (ojob)
      out_reg(A2f, p.Woutb, p.bout, p.out, Sq - 1, mo, pid,
              (short*)nullptr, tid, nullptr);
  }
}

// ================= host =================
extern "C" void kernel_launch(void* const* d_in, const int* in_sizes, int n_in,
                              void* d_out, int out_size, void* d_ws, size_t ws_size,
                              hipStream_t stream) {
  const float* z    = (const float*)d_in[0];
  const float* Wh   = (const float*)d_in[1];
  const float* bh   = (const float*)d_in[2];
  const float* Wc   = (const float*)d_in[3];
  const float* bc   = (const float*)d_in[4];
  const float* Wih0 = (const float*)d_in[5];
  const float* Whh0 = (const float*)d_in[6];
  const float* bih0 = (const float*)d_in[7];
  const float* bhh0 = (const float*)d_in[8];
  const float* Wih1 = (const float*)d_in[9];
  const float* Whh1 = (const float*)d_in[10];
  const float* bih1 = (const float*)d_in[11];
  const float* bhh1 = (const float*)d_in[12];
  const float* Wout = (const float*)d_in[13];
  const float* bout = (const float*)d_in[14];
  float* out = (float*)d_out;

  char* ws = (char*)d_ws;
  size_t off = 0;
  auto carve = [&](size_t bytes) { char* p = ws + off; off = (off + bytes + 255) & ~size_t(255); return p; };
  short* W1r   = (short*)carve((size_t)G4H * K1 * 2);
  short* W2r   = (short*)carve((size_t)G4H * K2q * 2);
  short* Woutb = (short*)carve((size_t)Od * Hd * 2);
  float* b0v   = (float*)carve(G4H * 4);
  float* b1v   = (float*)carve(G4H * 4);
  short* A1L   = (short*)carve((size_t)2 * 8 * A1LS * 2);   // 4 MB
  short* A2L   = (short*)carve((size_t)2 * 8 * A2LS * 2);   // 8 MB
  short* E1    = (short*)carve((size_t)Bt * 1024 * 2);      // 1 MB
  short* E2    = (short*)carve((size_t)Bt * 1024 * 2);      // 1 MB
  short* Eout  = (short*)carve((size_t)Bt * Od * 2);        // 64 KB
  short* Zb    = (short*)carve((size_t)Bt * Lz * 2);        // 128 KB
  float* c1    = (float*)carve((size_t)Bt * Hd * 4);
  float* c2    = (float*)carve((size_t)Bt * Hd * 4);
  int*   barr  = (int*)carve(1024);   // pairs: [pid*16]=cnt,gen,outcnt; slots at 128+

  k_conv_w1a<<<16384, 256, 0, stream>>>(Whh0, W1r);
  k_conv_w1c<<<2048, 256, 0, stream>>>(Wih0, W1r);
  k_conv_w1d<<<1024, 256, 0, stream>>>(Wih0, W1r);
  k_conv_w2 <<<32768, 256, 0, stream>>>(Wih1, Whh1, W2r);
  k_conv_wout<<<256, 256, 0, stream>>>(Wout, Woutb);
  k_vec<<<16, 256, 0, stream>>>(bih0, bhh0, bih1, bhh1, b0v, b1v, barr, (int*)Eout);
  k_init<<<2048, 256, 0, stream>>>(z, Wh, bh, Wc, bc, A1L, A2L, c1, c2);
  k_zb<<<256, 256, 0, stream>>>(z, Zb);

  Params pr{W1r, W2r, Woutb, b0v, b1v, bout,
            A1L, A2L, E1, E2, Eout, Zb, c1, c2, out, barr};

  (void)hipFuncSetAttribute((const void*)lstm_main,
                            hipFuncAttributeMaxDynamicSharedMemorySize, LDS_BYTES);
  lstm_main<<<dim3(NBLK), dim3(256), LDS_BYTES, stream>>>(pr);
}

// Round 7
// 11067.715 us; speedup vs baseline: 1.2484x; 1.2484x over previous
//
#include <hip/hip_runtime.h>

// Problem dims
#define Lz   128
#define Hd   1024
#define Od   64
#define Sq   256
#define Bt   512
#define K1   1216   // h1(1024) | z(128) | out(64)  -- fold un-materialized (rank-64)
#define K2q  2048   // h1n(1024) | h2(1024)
#define G4H  4096
#define NBLK 256u   // 8 XCD-teams x 32 blocks; team = batch-slice of 64 rows

typedef __attribute__((ext_vector_type(8))) short  short8;
typedef __attribute__((ext_vector_type(4))) float  floatx4;

__device__ __forceinline__ short f2bf(float x) {
  unsigned u = __float_as_uint(x);
  unsigned r = (u + 0x7fffu + ((u >> 16) & 1u)) >> 16;
  return (short)r;
}
__device__ __forceinline__ float sigf(float x)   { return 1.0f / (1.0f + __expf(-x)); }
__device__ __forceinline__ float tanhf_(float x) { return 1.0f - 2.0f / (__expf(2.0f * x) + 1.0f); }

// static data (z cols): full caching (L1+L2), reused every step
__device__ __forceinline__ void gl_lds_z(const short* g, void* l) {
  __builtin_amdgcn_global_load_lds(
      (__attribute__((address_space(1))) const void*)g,
      (__attribute__((address_space(3))) void*)l, 16, 0, 0);
}
// XCD-local activation load: sc0 only -> bypass (possibly stale) L1, hit the
// XCD's shared L2 where same-XCD producers' dirty lines live. No fabric trip.
__device__ __forceinline__ void gl_lds_a(const short* g, void* l) {
  __builtin_amdgcn_global_load_lds(
      (__attribute__((address_space(1))) const void*)g,
      (__attribute__((address_space(3))) void*)l, 16, 0, 1);
}
// weight stream: sc1 (device-scope) -> bypass the 4MB L2 (no thrash of the
// XCD-local activation lines; R6 lesson) but REMAIN MALL-cacheable: all
// 26.7MB of reordered weights live in the 256MB Infinity Cache after step 0,
// unlike R5's nt which forced half the stream to HBM (26GB FETCH).
__device__ __forceinline__ void gl_lds_w(const short* g, void* l) {
  __builtin_amdgcn_global_load_lds(
      (__attribute__((address_space(1))) const void*)g,
      (__attribute__((address_space(3))) void*)l, 16, 0, 16);
}
// h-state store: sc0 (L1 write-through) -> lands in the XCD's shared L2 (dirty,
// write-back). Intra-XCD coherent; no MALL write-through needed.
__device__ __forceinline__ void st_wt(short* p, short v) {
  asm volatile("global_store_short %0, %1, off sc0"
               :: "v"(p), "v"((unsigned)(unsigned short)v) : "memory");
}

#define S_BARRIER() asm volatile("s_barrier" ::: "memory")
#define WAITVM(n)   asm volatile("s_waitcnt vmcnt(" #n ")" ::: "memory")

// ---- per-XCD barrier over the 32-block team (relaxed agent atomics, proven
// pattern). __syncthreads drains vmem (compiler emits waitcnt before barrier),
// so epilogue stores are in L2 before the counter bump.
__device__ __forceinline__ void xbar(int* b) {   // b: [cnt, gen]
  __syncthreads();
  if (threadIdx.x == 0) {
    unsigned* cnt = (unsigned*)b;
    unsigned* gen = (unsigned*)b + 1;
    unsigned g = __hip_atomic_load(gen, __ATOMIC_RELAXED, __HIP_MEMORY_SCOPE_AGENT);
    unsigned a = __hip_atomic_fetch_add(cnt, 1u, __ATOMIC_RELAXED, __HIP_MEMORY_SCOPE_AGENT);
    if (a == 31u) {
      __hip_atomic_store(cnt, 0u, __ATOMIC_RELAXED, __HIP_MEMORY_SCOPE_AGENT);
      __hip_atomic_store(gen, g + 1u, __ATOMIC_RELAXED, __HIP_MEMORY_SCOPE_AGENT);
    } else {
      while (__hip_atomic_load(gen, __ATOMIC_RELAXED, __HIP_MEMORY_SCOPE_AGENT) == g)
        __builtin_amdgcn_s_sleep(8);
    }
  }
  __syncthreads();
}

// ---- weight row reorder: group bn (0..63) holds 64 rows: gate g (ifgo), j (0..15)
__device__ __forceinline__ int oldrow(int nr) {
  int bn = nr >> 6, rem = nr & 63, g = rem >> 4, jj = rem & 15;
  return g * Hd + bn * 16 + jj;
}

struct Params {
  const short *W1r, *W2r, *Woutb;
  const float *b0v, *b1v, *bout;
  short *A1_0, *A1_1, *A2_0, *A2_1;
  float *c1, *c2, *out;
  int *barr;   // 8 x 16 ints: per-XCD [cnt, gen, outcnt, teamreg, pad...]
};

// ================= prep kernels =================
__global__ void k_conv_w1a(const float* __restrict__ Whh0, short* __restrict__ W1r) {
  int idx = blockIdx.x * 256 + threadIdx.x;        // 4096*1024
  int nr = idx >> 10, k = idx & 1023;
  W1r[nr * K1 + k] = f2bf(Whh0[oldrow(nr) * Hd + k]);
}
__global__ void k_conv_w1c(const float* __restrict__ Wih0, short* __restrict__ W1r) {
  int idx = blockIdx.x * 256 + threadIdx.x;        // 4096*128 (z cols)
  int nr = idx >> 7, kz = idx & 127;
  W1r[nr * K1 + 1024 + kz] = f2bf(Wih0[oldrow(nr) * (Lz + Od) + kz]);
}
__global__ void k_conv_w1d(const float* __restrict__ Wih0, short* __restrict__ W1r) {
  int idx = blockIdx.x * 256 + threadIdx.x;        // 4096*64 (out-feedback cols)
  int nr = idx >> 6, j = idx & 63;
  W1r[nr * K1 + 1152 + j] = f2bf(Wih0[oldrow(nr) * (Lz + Od) + Lz + j]);
}
__global__ void k_conv_w2(const float* __restrict__ Wih1, const float* __restrict__ Whh1,
                          short* __restrict__ W2r) {
  int idx = blockIdx.x * 256 + threadIdx.x;        // 4096*2048
  int nr = idx >> 11, k = idx & 2047;
  int orow = oldrow(nr);
  float v = (k < Hd) ? Wih1[orow * Hd + k] : Whh1[orow * Hd + (k - Hd)];
  W2r[nr * K2q + k] = f2bf(v);
}
__global__ void k_conv_wout(const float* __restrict__ Wout, short* __restrict__ Woutb) {
  int idx = blockIdx.x * 256 + threadIdx.x;        // 64*1024
  Woutb[idx] = f2bf(Wout[idx]);
}
__global__ void k_vec(const float* __restrict__ bih0, const float* __restrict__ bhh0,
                      const float* __restrict__ bih1, const float* __restrict__ bhh1,
                      float* __restrict__ b0v, float* __restrict__ b1v,
                      int* __restrict__ barzero) {
  int n = blockIdx.x * 256 + threadIdx.x;          // 4096 (original gate order)
  if (n < 256) barzero[n] = 0;                     // zero barrier/team/outcnt state
  b0v[n] = bih0[n] + bhh0[n];
  b1v[n] = bih1[n] + bhh1[n];
}
__global__ void k_init(const float* __restrict__ z, const float* __restrict__ Wh,
                       const float* __restrict__ bh, const float* __restrict__ Wc,
                       const float* __restrict__ bc,
                       short* __restrict__ A1_0, short* __restrict__ A2_0,
                       float* __restrict__ c1, float* __restrict__ c2) {
  int idx = blockIdx.x * 256 + threadIdx.x;        // 512*1024
  int m = idx >> 10, n = idx & 1023;
  const float* zr = z + m * Lz;
  const float* whr = Wh + n * Lz;
  const float* wcr = Wc + n * Lz;
  float hh = bh[n], cc = bc[n];
  #pragma unroll 8
  for (int k = 0; k < Lz; ++k) { float zv = zr[k]; hh += zv * whr[k]; cc += zv * wcr[k]; }
  c1[idx] = cc;
  c2[idx] = cc;
  short hb = f2bf(hh);
  A1_0[m * K1 + n] = hb;                 // h1(-1) = h0
  if (n < Od) A1_0[m * K1 + 1152 + n] = 0;   // out(-1) = 0
  A2_0[m * K2q + Hd + n] = hb;           // h2(-1) = h0
}
__global__ void k_initz(const float* __restrict__ z, short* __restrict__ A1_0,
                        short* __restrict__ A1_1) {
  int idx = blockIdx.x * 256 + threadIdx.x;        // 512*128
  int m = idx >> 7, k = idx & 127;
  short v = f2bf(z[idx]);
  A1_0[m * K1 + 1024 + k] = v;
  A1_1[m * K1 + 1024 + k] = v;
}

// ================= main persistent kernel =================
#define MFMA16(a, b, c) __builtin_amdgcn_mfma_f32_16x16x32_bf16(a, b, c, 0, 0, 0)
#define BUFSH 12288   // shorts per ring buffer: A 64x64 (4096) + W 128x64 (8192)
#define NBUF  5       // ring depth: prefetch 3, single barrier/chunk (needs >= depth+2)
#define LDS_BYTES (NBUF * BUFSH * 2)   // 120 KB -> exactly 1 block/CU

// ---- folded out-projection, register-based: 4 blocks/XCD (slots 0,8,16,24),
// 16 batch rows each. h2 rows read from the XCD's L2 (sc0); Wout cached.
// Exact-count vmcnt pipelining, 2 groups deep. (R2-verified compute core.)
__device__ __forceinline__ void out_reg(const short* __restrict__ h2src,
    const short* __restrict__ Wo, const float* __restrict__ boutv,
    float* __restrict__ outp, int tt, int mo,
    short* __restrict__ ofb, int tid, int* __restrict__ ocnt)
{
  const int lane = tid & 63, w = tid >> 6;
  const int l15 = lane & 15, q = lane >> 4;
  const short* ap = h2src + (size_t)(mo + l15) * K2q + Hd + q * 8;
  const short* bp = Wo + (size_t)(w * 16 + l15) * Hd + q * 8;
  floatx4 acc = {};
  short8 A0, B0, A1, B1, A2, B2, A3, B3;
#define OLA(r, kk) asm volatile("global_load_dwordx4 %0, %1, off sc0" \
    : "=v"(r) : "v"(ap + (kk) * 32) : "memory")
#define OLB(r, kk) asm volatile("global_load_dwordx4 %0, %1, off" \
    : "=v"(r) : "v"(bp + (kk) * 32) : "memory")
  OLA(A0, 0); OLB(B0, 0); OLA(A1, 1); OLB(B1, 1);     // group 0 (kk 0,1)
  OLA(A2, 2); OLB(B2, 2); OLA(A3, 3); OLB(B3, 3);     // group 1 (kk 2,3)
  #pragma unroll
  for (int g = 0; g < 16; g += 2) {
    WAITVM(4); __builtin_amdgcn_sched_barrier(0);      // group g retired
    acc = MFMA16(A0, B0, acc); acc = MFMA16(A1, B1, acc);
    if (g + 2 < 16) { OLA(A0, 2*(g+2)); OLB(B0, 2*(g+2));
                      OLA(A1, 2*(g+2)+1); OLB(B1, 2*(g+2)+1); }
    if (g + 3 < 16) { WAITVM(4); } else { WAITVM(0); } // group g+1 retired
    __builtin_amdgcn_sched_barrier(0);
    acc = MFMA16(A2, B2, acc); acc = MFMA16(A3, B3, acc);
    if (g + 3 < 16) { OLA(A2, 2*(g+3)); OLB(B2, 2*(g+3));
                      OLA(A3, 2*(g+3)+1); OLB(B3, 2*(g+3)+1); }
  }
#undef OLA
#undef OLB
  #pragma unroll
  for (int r = 0; r < 4; ++r) {
    int m = mo + q * 4 + r;
    int n = w * 16 + l15;
    float v = acc[r] + boutv[n];
    outp[(size_t)m * (Sq * Od) + (size_t)tt * Od + n] = v;
    if (ofb) st_wt(ofb + (size_t)m * K1 + 1152 + n, f2bf(v));
  }
  WAITVM(0);          // each wave drains its own feedback stores
  __syncthreads();    // all waves' stores in L2 before publishing
  if (ocnt && tid == 0)
    __hip_atomic_fetch_add(ocnt, 1, __ATOMIC_RELAXED, __HIP_MEMORY_SCOPE_AGENT);
}

// 64x128 tile, 4 waves (R0-proven core): w = mh*2+gh. XOR-swizzled LDS:
// chunk-slot sl of row r holds global chunk sl^(r&7). Ring NBUF=5, depth 3,
// SINGLE barrier per chunk:
//   stage(kk+3) -> buf (kk+3)%5 ; WAITVM ; S_BARRIER ; compute buf kk%5
// Overwrite safety: buf (kk+3)%5 == buf (kk-2)%5 was last read in
// compute(kk-2), which ALL waves finished before barrier(kk-1), which this
// wave has passed before issuing stage(kk+3). Read safety: every wave's own
// WAITVM retires its stage(kk) portion before its barrier(kk) arrival.
__device__ __forceinline__ void gemm_win(
    const short* __restrict__ Asrc, int astride, int nk, int zstart,
    const short* __restrict__ Wsrc,
    const float* __restrict__ bz, float cr[2][4],
    short* __restrict__ hd0, int hs0, int ho0,
    short* __restrict__ hd1, int hs1, int ho1,
    int m0, int bn2, short* sm, int tid,
    int* __restrict__ ocnt, int othresh)
{
  const int lane = tid & 63, w = tid >> 6;
  const int l15 = lane & 15, q = lane >> 4;
  const int mh = w >> 1, gh = w & 1;
  floatx4 acc[2][4] = {};

  const short* Ab = Asrc + (size_t)m0 * astride;
  const short* Wb = Wsrc + (size_t)(bn2 * 128) * astride;

  auto stage = [&](int kk, int b) {
    const int kb = kk * 64;
    short* as = sm + b * BUFSH;
    short* ws = as + 4096;
    const bool stat = (kk == zstart) || (kk == zstart + 1);   // static z cols
    #pragma unroll
    for (int i = 0; i < 2; ++i) {
      int s = i * 256 + tid;
      int row = s >> 3, cg = (s & 7) ^ (row & 7);
      const short* gp = Ab + (size_t)row * astride + kb + cg * 8;
      if (stat) gl_lds_z(gp, as + s * 8);
      else      gl_lds_a(gp, as + s * 8);
    }
    #pragma unroll
    for (int i = 0; i < 4; ++i) {
      int s = i * 256 + tid;
      int row = s >> 3, cg = (s & 7) ^ (row & 7);
      gl_lds_w(Wb + (size_t)row * astride + kb + cg * 8, ws + s * 8);
    }
  };

  stage(0, 0);
  stage(1, 1);
  stage(2, 2);
  for (int kk = 0; kk < nk; ++kk) {
    if (kk + 3 < nk) {
      if (ocnt && kk + 3 == nk - 1) {     // out-feedback chunk: wait for out-jobs
        while (__hip_atomic_load(ocnt, __ATOMIC_RELAXED, __HIP_MEMORY_SCOPE_AGENT) < othresh)
          __builtin_amdgcn_s_sleep(1);
      }
      stage(kk + 3, (kk + 3) % NBUF);
      WAITVM(18);
    }
    else if (kk + 2 < nk) { WAITVM(12); }
    else if (kk + 1 < nk) { WAITVM(6); }
    else { WAITVM(0); }
    S_BARRIER();
    const short* as = sm + (kk % NBUF) * BUFSH;
    const short* ws = as + 4096;
    #pragma unroll
    for (int ks = 0; ks < 2; ++ks) {
      const int cc = ks * 4 + q;
      short8 a[2];
      #pragma unroll
      for (int mt = 0; mt < 2; ++mt) {
        const int ra = mh * 32 + mt * 16 + l15;
        a[mt] = *(const short8*)(as + (ra * 8 + (cc ^ (ra & 7))) * 8);
      }
      #pragma unroll
      for (int g = 0; g < 4; ++g) {
        const int rw = gh * 64 + g * 16 + l15;
        short8 b = *(const short8*)(ws + (rw * 8 + (cc ^ (rw & 7))) * 8);
        acc[0][g] = MFMA16(a[0], b, acc[0][g]);
        acc[1][g] = MFMA16(a[1], b, acc[1][g]);
      }
    }
  }
  // fused LSTM cell epilogue; h stored to the XCD-shared L2 (sc0)
  #pragma unroll
  for (int mt = 0; mt < 2; ++mt) {
    #pragma unroll
    for (int r = 0; r < 4; ++r) {
      const int mg = m0 + mh * 32 + mt * 16 + q * 4 + r;
      const int colh = bn2 * 32 + gh * 16 + l15;
      float iv = acc[mt][0][r] + bz[0];
      float fv = acc[mt][1][r] + bz[1];
      float gv = acc[mt][2][r] + bz[2];
      float ov = acc[mt][3][r] + bz[3];
      float cn = sigf(fv) * cr[mt][r] + sigf(iv) * tanhf_(gv);
      cr[mt][r] = cn;
      short hb = f2bf(sigf(ov) * tanhf_(cn));
      st_wt(hd0 + (size_t)mg * hs0 + ho0 + colh, hb);
      if (hd1) st_wt(hd1 + (size_t)mg * hs1 + ho1 + colh, hb);
    }
  }
}

__global__ __launch_bounds__(256, 1) void lstm_main(Params p) {
  extern __shared__ __align__(16) short smem[];   // 5 x 24 KB = 120 KB
  const int tid = threadIdx.x;

  // ---- dynamic XCD-team formation: correctness does NOT depend on the
  // blockIdx->XCD mapping. Each block joins the team of the XCD it actually
  // runs on; 120KB LDS guarantees 1 block/CU -> exactly 32 blocks per XCD.
  __shared__ int sh_ids[2];
  if (tid == 0) {
    unsigned xr;
    asm volatile("s_getreg_b32 %0, hwreg(HW_REG_XCC_ID)" : "=s"(xr));
    int xcc = (int)(xr & 7u);
    int slot = (int)__hip_atomic_fetch_add((unsigned*)(p.barr + xcc * 16 + 3), 1u,
                                           __ATOMIC_RELAXED, __HIP_MEMORY_SCOPE_AGENT);
    sh_ids[0] = xcc;
    sh_ids[1] = slot & 31;
  }
  __syncthreads();
  const int xcc  = sh_ids[0];
  const int slot = sh_ids[1];
  int* xb = p.barr + xcc * 16;          // [0]=cnt [1]=gen [2]=outcnt

  const int m0 = xcc * 64;              // this XCD's batch slice (64 rows)
  const int bn2 = slot;                 // gate-col slice: h-cols [slot*32, +32)
  const bool ojob = ((slot & 7) == 0);  // 4 out-jobs per XCD
  const int mo = xcc * 64 + (slot >> 3) * 16;   // out-job batch rows (16 each)

  const int lane = tid & 63, w = tid >> 6;
  const int l15 = lane & 15, q = lane >> 4;
  const int mh = w >> 1, gh = w & 1;
  const int colh = bn2 * 32 + gh * 16 + l15;

  float bA[4], bB[4], c1r[2][4], c2r[2][4];
  #pragma unroll
  for (int g = 0; g < 4; ++g) {
    bA[g] = p.b0v[g * Hd + colh];
    bB[g] = p.b1v[g * Hd + colh];
  }
  #pragma unroll
  for (int mt = 0; mt < 2; ++mt)
    #pragma unroll
    for (int r = 0; r < 4; ++r) {
      const int mg = m0 + mh * 32 + mt * 16 + q * 4 + r;
      c1r[mt][r] = p.c1[mg * Hd + colh];
      c2r[mt][r] = p.c2[mg * Hd + colh];
    }

  for (int t = 0; t < Sq; ++t) {
    const int par = t & 1;
    const short* A1p = par ? p.A1_1 : p.A1_0;
    short* A1n = par ? p.A1_0 : p.A1_1;
    short* A2p = par ? p.A2_1 : p.A2_0;
    short* A2n = par ? p.A2_0 : p.A2_1;
    // out(t-1) on designated blocks (reads h2(t-1) from this XCD's L2, writes
    // feedback into A1p out-segment + bumps outcnt). Other blocks proceed into
    // window A and only wait at the out-feedback chunk.
    if (ojob && t > 0)
      out_reg(A2p, p.Woutb, p.bout, p.out, t - 1, mo, (short*)A1p, tid, xb + 2);
    // window A: layer-0 gates; A1 = [h1 | z | out(t-1)], out-chunk flag-guarded
    gemm_win(A1p, K1, 19, 16, p.W1r, bA, c1r,
             A1n, K1, 0, (short*)A2p, K2q, 0, m0, bn2, smem, tid,
             xb + 2, 4 * t);
    xbar(xb);
    // window B: layer-1 gates; h2n only into A2n
    gemm_win(A2p, K2q, 32, -2, p.W2r, bB, c2r,
             A2n, K2q, Hd, (short*)nullptr, 0, 0, m0, bn2, smem, tid,
             nullptr, 0);
    xbar(xb);
  }
  // final: out(255) from h2(255) in A2_0 (phase B of t=255 wrote A2n = A2_0)
  if (ojob)
    out_reg(p.A2_0, p.Woutb, p.bout, p.out, Sq - 1, mo, (short*)nullptr, tid, nullptr);
}

// ================= host =================
extern "C" void kernel_launch(void* const* d_in, const int* in_sizes, int n_in,
                              void* d_out, int out_size, void* d_ws, size_t ws_size,
                              hipStream_t stream) {
  const float* z    = (const float*)d_in[0];
  const float* Wh   = (const float*)d_in[1];
  const float* bh   = (const float*)d_in[2];
  const float* Wc   = (const float*)d_in[3];
  const float* bc   = (const float*)d_in[4];
  const float* Wih0 = (const float*)d_in[5];
  const float* Whh0 = (const float*)d_in[6];
  const float* bih0 = (const float*)d_in[7];
  const float* bhh0 = (const float*)d_in[8];
  const float* Wih1 = (const float*)d_in[9];
  const float* Whh1 = (const float*)d_in[10];
  const float* bih1 = (const float*)d_in[11];
  const float* bhh1 = (const float*)d_in[12];
  const float* Wout = (const float*)d_in[13];
  const float* bout = (const float*)d_in[14];
  float* out = (float*)d_out;

  char* ws = (char*)d_ws;
  size_t off = 0;
  auto carve = [&](size_t bytes) { char* p = ws + off; off = (off + bytes + 255) & ~size_t(255); return p; };
  short* W1r   = (short*)carve((size_t)G4H * K1 * 2);
  short* W2r   = (short*)carve((size_t)G4H * K2q * 2);
  short* Woutb = (short*)carve((size_t)Od * Hd * 2);
  float* b0v   = (float*)carve(G4H * 4);
  float* b1v   = (float*)carve(G4H * 4);
  short* A1_0  = (short*)carve((size_t)Bt * K1 * 2);
  short* A1_1  = (short*)carve((size_t)Bt * K1 * 2);
  short* A2_0  = (short*)carve((size_t)Bt * K2q * 2);
  short* A2_1  = (short*)carve((size_t)Bt * K2q * 2);
  float* c1    = (float*)carve((size_t)Bt * Hd * 4);
  float* c2    = (float*)carve((size_t)Bt * Hd * 4);
  int*   barr  = (int*)carve(1024);  // 8 XCDs x 16 ints: [cnt,gen,outcnt,team,...]

  k_conv_w1a<<<16384, 256, 0, stream>>>(Whh0, W1r);
  k_conv_w1c<<<2048, 256, 0, stream>>>(Wih0, W1r);
  k_conv_w1d<<<1024, 256, 0, stream>>>(Wih0, W1r);
  k_conv_w2 <<<32768, 256, 0, stream>>>(Wih1, Whh1, W2r);
  k_conv_wout<<<256, 256, 0, stream>>>(Wout, Woutb);
  k_vec<<<16, 256, 0, stream>>>(bih0, bhh0, bih1, bhh1, b0v, b1v, barr);
  k_init<<<2048, 256, 0, stream>>>(z, Wh, bh, Wc, bc, A1_0, A2_0, c1, c2);
  k_initz<<<256, 256, 0, stream>>>(z, A1_0, A1_1);

  Params pr{W1r, W2r, Woutb, b0v, b1v, bout,
            A1_0, A1_1, A2_0, A2_1, c1, c2, out, barr};

  (void)hipFuncSetAttribute((const void*)lstm_main,
                            hipFuncAttributeMaxDynamicSharedMemorySize, LDS_BYTES);
  lstm_main<<<dim3(NBLK), dim3(256), LDS_BYTES, stream>>>(pr);
}